// Round 15
// baseline (314.958 us; speedup 1.0000x reference)
//
#include <hip/hip_runtime.h>
#include <hip/hip_bf16.h>

#define PI_F 3.14159265358979323846f
#define KPAD 260               // LDS act row stride in fp16 (520 B -> 2-way bank aliasing = free)

typedef _Float16 h8 __attribute__((ext_vector_type(8)));
typedef _Float16 h4 __attribute__((ext_vector_type(4)));
typedef _Float16 h2 __attribute__((ext_vector_type(2)));
typedef __fp16 fp16x2 __attribute__((ext_vector_type(2)));
typedef float f32x16 __attribute__((ext_vector_type(16)));

__device__ __forceinline__ h2 cvt_pk_h2(float a, float b)
{
    fp16x2 r = __builtin_amdgcn_cvt_pkrtz(a, b);
    return __builtin_bit_cast(h2, r);
}

// ---- d_ws: fp16 weights, fragment-packed ----
// block (ntile*KT + kt) -> 1KB blob; lane l's h8 at byte l*16:
//   W_T[n = ntile*32 + (l&31)][k = kt*16 + (l>>5)*8 + 0..7]
#define OFF_DIN   0          // 8 ntiles, KT=6   (K=96 pad, N=256)
#define OFF_DHID  24576      // 6 x (8 ntiles, KT=16)
#define OFF_FEAT  417792     // 8 ntiles, KT=16  (N=256: Wd_out[k][n+1])
#define OFF_CIN   483328     // 4 ntiles, KT=16  (N=128)
#define OFF_CHID  516096     // 2 x (4 ntiles, KT=8)
#define OFF_COUT  548864     // 1 ntile,  KT=8   (n<3 -> Wc_out[k][n]; else 0)
#define W_TOTAL   552960
// ---- f32 bias fragments after weights: per ntile 32 f32 = [lq][reg j],
//      value = bias[ntile*32 + (j&3) + 8*(j>>2) + 4*lq] ----
#define FB_DIN  0            // 256
#define FB_DHID 256          // 6 x 256
#define FB_FEAT 1792         // 256  (bd_out[n+1])
#define FB_CIN  2048         // 128
#define FB_CHID 2176         // 2 x 128
#define FB_WD0  2432         // 256: Wd_out[k*257]  (density weight column, plain order)
#define FB_BD0  2688         // 1:   bd_out[0]
#define B_TOTAL 2689
#define PREP_TOTAL (W_TOTAL + B_TOTAL)

__global__ void prep_kernel(const float* __restrict__ Wd_in,  const float* __restrict__ Wd_hid,
                            const float* __restrict__ Wd_out, const float* __restrict__ Wc_in,
                            const float* __restrict__ Wc_hid, const float* __restrict__ Wc_out,
                            const float* __restrict__ bd_in,  const float* __restrict__ bd_hid,
                            const float* __restrict__ bd_out, const float* __restrict__ bc_in,
                            const float* __restrict__ bc_hid,
                            _Float16* __restrict__ wdst, float* __restrict__ bdst)
{
    int i = blockIdx.x * 256 + threadIdx.x;
    if (i >= PREP_TOTAL) return;
    if (i < W_TOTAL) {
        float v = 0.f;
        int j, n, k;
        #define DECODE(jj, KTv)  do { int frag = (jj) >> 3; int e = (jj) & 7;          \
                                      int lane = frag & 63; int tk = frag >> 6;         \
                                      int ntl = tk / (KTv); int kt = tk % (KTv);        \
                                      n = ntl * 32 + (lane & 31);                       \
                                      k = kt * 16 + (lane >> 5) * 8 + e; } while (0)
        if (i < OFF_DHID) {
            j = i; DECODE(j, 6);
            if (k < 75) v = Wd_in[k * 256 + n];
        } else if (i < OFF_FEAT) {
            j = i - OFF_DHID; int l = j >> 16; j &= 65535; DECODE(j, 16);
            v = Wd_hid[(l * 256 + k) * 256 + n];
        } else if (i < OFF_CIN) {
            j = i - OFF_FEAT; DECODE(j, 16);
            v = Wd_out[k * 257 + n + 1];
        } else if (i < OFF_CHID) {
            j = i - OFF_CIN; DECODE(j, 16);
            v = Wc_in[k * 128 + n];
        } else if (i < OFF_COUT) {
            j = i - OFF_CHID; int l = j >> 14; j &= 16383; DECODE(j, 8);
            v = Wc_hid[(l * 128 + k) * 128 + n];
        } else {
            j = i - OFF_COUT; DECODE(j, 8);
            if (n < 3) v = Wc_out[k * 3 + n];
        }
        #undef DECODE
        wdst[i] = (_Float16)v;
    } else {
        int b = i - W_TOTAL;
        float v = 0.f;
        #define BDECODE(bb) int ntl = (bb) >> 5; int r5 = (bb) & 31;                   \
                            int lq = r5 >> 4, jj = r5 & 15;                            \
                            int n = ntl * 32 + (jj & 3) + 8 * (jj >> 2) + 4 * lq
        if (b < FB_DHID)      { BDECODE(b); v = bd_in[n]; }
        else if (b < FB_FEAT) { int b2 = b - FB_DHID; int l = b2 >> 8; int bb = b2 & 255;
                                BDECODE(bb); v = bd_hid[l * 256 + n]; }
        else if (b < FB_CIN)  { int bb = b - FB_FEAT; BDECODE(bb); v = bd_out[n + 1]; }
        else if (b < FB_CHID) { int bb = b - FB_CIN; BDECODE(bb); v = bc_in[n]; }
        else if (b < FB_WD0)  { int b2 = b - FB_CHID; int l = b2 >> 7; int bb = b2 & 127;
                                BDECODE(bb); v = bc_hid[l * 128 + n]; }
        else if (b < FB_BD0)  { int k = b - FB_WD0; v = Wd_out[k * 257]; }
        else                  { v = bd_out[0]; }
        #undef BDECODE
        bdst[b] = v;
    }
}

__device__ __forceinline__ h8 lds_read_h8(const _Float16* p)
{
    h4 lo = *(const h4*)(p);
    h4 hi = *(const h4*)(p + 4);
    return __builtin_shufflevector(lo, hi, 0, 1, 2, 3, 4, 5, 6, 7);
}

// One dense layer. 8 THIN waves, wave (r,c): r in {0,1} -> rows r*64..+63 (2 mtiles),
// c in {0..3} -> ntiles c*NT..+NT-1 (NT=2 for N=256). 128 points per block.
// acc = 64 regs/wave -> 4 waves/SIMD at <=128 VGPR; two independent blocks' barrier
// domains per SIMD give cross-wave load/MFMA overlap. kt loop fully unrolled.
// acc initialized with fragment-packed bias. Packed-f16 epilogue.
// DDOT: before the barrier, density partial dot, k-slice [wid*32,+32), m = lane, lane+64.
template<int KT, int NT, int MT, bool RELU, bool DDOT>
__device__ __forceinline__ void dense(_Float16 (*At)[KPAD],
                                      const _Float16* __restrict__ WP,
                                      const float* __restrict__ bfrag,
                                      const float* __restrict__ wd0,
                                      float (*dpart)[128],
                                      int rbase, int ntile0, int wid,
                                      int lrow, int lq, int lane)
{
    f32x16 acc[MT][NT];
#pragma unroll
    for (int nt = 0; nt < NT; ++nt) {
        f32x16 b = *(const f32x16*)(bfrag + (ntile0 + nt) * 32 + lq * 16);
#pragma unroll
        for (int mt = 0; mt < MT; ++mt)
            acc[mt][nt] = b;
    }

    const _Float16* wbase = WP + ((size_t)ntile0 * KT) * 512 + (size_t)lane * 8;

#pragma unroll
    for (int kt = 0; kt < KT; ++kt) {
        const int koff = kt * 16 + lq * 8;
        h8 wf[NT];
#pragma unroll
        for (int nt = 0; nt < NT; ++nt)
            wf[nt] = *(const h8*)(wbase + (size_t)(nt * KT + kt) * 512);
        h8 af[MT];
#pragma unroll
        for (int mt = 0; mt < MT; ++mt)
            af[mt] = lds_read_h8(&At[rbase + mt * 32 + lrow][koff]);
#pragma unroll
        for (int mt = 0; mt < MT; ++mt)
#pragma unroll
            for (int nt = 0; nt < NT; ++nt)
                acc[mt][nt] = __builtin_amdgcn_mfma_f32_32x32x16_f16(wf[nt], af[mt], acc[mt][nt], 0, 0, 0);
    }

    if (DDOT) {
        // density partial: k-slice [wid*32, +32) of current h, for m = lane and lane+64
        const float* w0 = wd0 + wid * 32;
#pragma unroll
        for (int m2 = 0; m2 < 2; ++m2) {
            const int m = lane + m2 * 64;
            float s = 0.f;
#pragma unroll
            for (int kk = 0; kk < 32; kk += 8) {
                h8 hv = lds_read_h8(&At[m][wid * 32 + kk]);
#pragma unroll
                for (int e = 0; e < 8; ++e)
                    s = fmaf((float)hv[e], w0[kk + e], s);
            }
            dpart[wid][m] = s;
        }
    }

    __syncthreads();   // all reads of At done

#pragma unroll
    for (int mt = 0; mt < MT; ++mt) {
        const int m = rbase + mt * 32 + lrow;
#pragma unroll
        for (int nt = 0; nt < NT; ++nt) {
#pragma unroll
            for (int p = 0; p < 4; ++p) {
                const int n0 = (ntile0 + nt) * 32 + p * 8 + lq * 4;
                h2 lo = cvt_pk_h2(acc[mt][nt][4 * p + 0], acc[mt][nt][4 * p + 1]);
                h2 hi = cvt_pk_h2(acc[mt][nt][4 * p + 2], acc[mt][nt][4 * p + 3]);
                h4 hv = __builtin_shufflevector(lo, hi, 0, 1, 2, 3);
                if (RELU) {
                    const h4 zero = {(_Float16)0, (_Float16)0, (_Float16)0, (_Float16)0};
                    hv = __builtin_elementwise_max(hv, zero);
                }
                *(h4*)(&At[m][n0]) = hv;
            }
        }
    }
    __syncthreads();   // At ready for next layer
}

__global__ __launch_bounds__(512)
__attribute__((amdgpu_waves_per_eu(4, 4)))
void ffmlp_kernel(const float* __restrict__ mean, const float* __restrict__ cov,
                  const int* __restrict__ decayscale,
                  const _Float16* __restrict__ wws, const float* __restrict__ bws,
                  const float* __restrict__ bc_out,
                  float* __restrict__ out, int N)
{
    __shared__ __align__(16) _Float16 At[128][KPAD];
    __shared__ float dpart[8][128];

    const int t = threadIdx.x;
    const int wid = t >> 6, lane = t & 63;       // 8 waves
    const int r = wid >> 2, c = wid & 3;         // r: row half, c: ntile quarter
    const int lrow = lane & 31, lq = lane >> 5;
    const int rbase = r * 64;
    const int p0 = blockIdx.x * 128;

    // ---- Fourier embedding (fp32 math, fp16 store). 4 threads per point. ----
    {
        const int m = t >> 2, q = t & 3;
        const long pt = (long)p0 + m;
        float x0 = 0.f, x1 = 0.f, x2 = 0.f, v0 = 0.f, v1 = 0.f, v2 = 0.f;
        if (pt < N) {
            x0 = mean[pt * 3 + 0]; x1 = mean[pt * 3 + 1]; x2 = mean[pt * 3 + 2];
            v0 = cov[pt * 9 + 0];  v1 = cov[pt * 9 + 4];  v2 = cov[pt * 9 + 8];
        }
        const float dec = (float)(*decayscale);
        if (q == 0) {
            At[m][0] = (_Float16)x0; At[m][1] = (_Float16)x1; At[m][2] = (_Float16)x2;
            for (int k = 75; k < 80; ++k) At[m][k] = (_Float16)0.f;
        } else {
            for (int k = 75 + 5 * q; k < (q == 3 ? 96 : 80 + 5 * q); ++k) At[m][k] = (_Float16)0.f;
        }
        const float xs[3] = {x0, x1, x2}, vs[3] = {v0, v1, v2};
#pragma unroll
        for (int fi = 0; fi < 3; ++fi) {
            const int f = q * 3 + fi;
            const float fs = (float)(1 << f);
            const float wcl = fminf(fmaxf(dec - (float)f, 0.f), 1.f);
            const float win = 0.5f * (1.f - cosf(wcl * PI_F));
#pragma unroll
            for (int d = 0; d < 3; ++d) {
                const float xb = xs[d] * fs;
                const float att = expf(-0.5f * vs[d] * fs * fs) * win;
                float s, co;
                sincosf(xb, &s, &co);
                At[m][3 + 6 * f + d] = (_Float16)(s * att);
                At[m][6 + 6 * f + d] = (_Float16)(co * att);
            }
        }
    }
    __syncthreads();

    // ---- density MLP ----
    dense<6, 2, 2, true, false>(At, wws + OFF_DIN, bws + FB_DIN, bws, dpart,
                                rbase, c * 2, wid, lrow, lq, lane);
#pragma unroll 1
    for (int i = 0; i < 6; ++i)
        dense<16, 2, 2, true, false>(At, wws + OFF_DHID + i * 65536, bws + FB_DHID + i * 256,
                                     bws, dpart, rbase, c * 2, wid, lrow, lq, lane);
    // FEAT (no relu) + density partial dot on the pre-overwrite h
    dense<16, 2, 2, false, true>(At, wws + OFF_FEAT, bws + FB_FEAT, bws + FB_WD0, dpart,
                                 rbase, c * 2, wid, lrow, lq, lane);

    // ---- color MLP ----
    dense<16, 1, 2, true, false>(At, wws + OFF_CIN, bws + FB_CIN, bws, dpart,
                                 rbase, c, wid, lrow, lq, lane);
#pragma unroll 1
    for (int i = 0; i < 2; ++i)
        dense<8, 1, 2, true, false>(At, wws + OFF_CHID + i * 16384, bws + FB_CHID + i * 128,
                                    bws, dpart, rbase, c, wid, lrow, lq, lane);

    // ---- output layer: 128 -> 16 (rgb cols 0..2), c==0 waves (r covers m-half) ----
    if (c == 0) {
        f32x16 acc[2];
#pragma unroll
        for (int mt = 0; mt < 2; ++mt)
#pragma unroll
            for (int j = 0; j < 16; ++j) acc[mt][j] = 0.f;
        const _Float16* wco = wws + OFF_COUT + (size_t)lane * 8;
#pragma unroll
        for (int kt = 0; kt < 8; ++kt) {
            const int koff = kt * 16 + lq * 8;
            h8 wf = *(const h8*)(wco + (size_t)kt * 512);
#pragma unroll
            for (int mt = 0; mt < 2; ++mt) {
                h8 af = lds_read_h8(&At[rbase + mt * 32 + lrow][koff]);
                acc[mt] = __builtin_amdgcn_mfma_f32_32x32x16_f16(wf, af, acc[mt], 0, 0, 0);
            }
        }
        const float bc0 = bc_out[0], bc1 = bc_out[1], bc2 = bc_out[2];
        const float bd0 = bws[FB_BD0];
        if (lq == 0) {
#pragma unroll
            for (int mt = 0; mt < 2; ++mt) {
                const int m = rbase + mt * 32 + lrow;
                const long pt = (long)p0 + m;
                if (pt < N) {
                    float dsum = bd0;
#pragma unroll
                    for (int w = 0; w < 8; ++w) dsum += dpart[w][m];
                    float4 o;
                    o.x = acc[mt][0] + bc0;
                    o.y = acc[mt][1] + bc1;
                    o.z = acc[mt][2] + bc2;
                    o.w = dsum;
                    *(float4*)(out + pt * 4) = o;
                }
            }
        }
    }
}

extern "C" void kernel_launch(void* const* d_in, const int* in_sizes, int n_in,
                              void* d_out, int out_size, void* d_ws, size_t ws_size,
                              hipStream_t stream)
{
    const float* mean   = (const float*)d_in[0];
    const float* cov    = (const float*)d_in[1];
    const float* Wd_in  = (const float*)d_in[2];
    const float* bd_in  = (const float*)d_in[3];
    const float* Wd_hid = (const float*)d_in[4];
    const float* bd_hid = (const float*)d_in[5];
    const float* Wd_out = (const float*)d_in[6];
    const float* bd_out = (const float*)d_in[7];
    const float* Wc_in  = (const float*)d_in[8];
    const float* bc_in  = (const float*)d_in[9];
    const float* Wc_hid = (const float*)d_in[10];
    const float* bc_hid = (const float*)d_in[11];
    const float* Wc_out = (const float*)d_in[12];
    const float* bc_out = (const float*)d_in[13];
    const int*   decay  = (const int*)d_in[14];

    _Float16* wws = (_Float16*)d_ws;
    float*    bws = (float*)((char*)d_ws + (size_t)W_TOTAL * 2);

    const int N = in_sizes[0] / 3;     // 262144 points

    const int prep_blocks = (PREP_TOTAL + 255) / 256;
    prep_kernel<<<prep_blocks, 256, 0, stream>>>(Wd_in, Wd_hid, Wd_out, Wc_in, Wc_hid, Wc_out,
                                                 bd_in, bd_hid, bd_out, bc_in, bc_hid, wws, bws);

    const int blocks = (N + 127) / 128;
    ffmlp_kernel<<<blocks, 512, 0, stream>>>(mean, cov, decay, wws, bws, bc_out, (float*)d_out, N);
}

// Round 17
// 286.318 us; speedup vs baseline: 1.1000x; 1.1000x over previous
//
#include <hip/hip_runtime.h>
#include <hip/hip_bf16.h>

#define PI_F 3.14159265358979323846f
#define KPAD 260               // LDS act row stride in fp16 (520 B -> 2-way bank aliasing = free)

typedef _Float16 h8 __attribute__((ext_vector_type(8)));
typedef _Float16 h4 __attribute__((ext_vector_type(4)));
typedef _Float16 h2 __attribute__((ext_vector_type(2)));
typedef __fp16 fp16x2 __attribute__((ext_vector_type(2)));
typedef float f32x16 __attribute__((ext_vector_type(16)));
typedef unsigned int u32x4 __attribute__((ext_vector_type(4)));

__device__ __forceinline__ h2 cvt_pk_h2(float a, float b)
{
    fp16x2 r = __builtin_amdgcn_cvt_pkrtz(a, b);
    return __builtin_bit_cast(h2, r);
}

// SRSRC covering the whole packed-weight region: OOB reads return 0, never fault.
__device__ __forceinline__ u32x4 make_srsrc(const void* p, unsigned bytes)
{
    unsigned long long a = (unsigned long long)p;
    u32x4 r;
    r.x = (unsigned)a;
    r.y = (unsigned)(a >> 32);     // stride = 0
    r.z = bytes;                   // num_records (bytes, stride==0)
    r.w = 0x00020000u;             // raw dword access
    return r;
}

// counted vmcnt wait + scheduler fence (rule 18: sched_barrier right after asm waitcnt)
template<int N>
__device__ __forceinline__ void vm_wait()
{
    if constexpr (N >= 6)      asm volatile("s_waitcnt vmcnt(6)" ::: "memory");
    else if constexpr (N == 5) asm volatile("s_waitcnt vmcnt(5)" ::: "memory");
    else if constexpr (N == 4) asm volatile("s_waitcnt vmcnt(4)" ::: "memory");
    else if constexpr (N == 3) asm volatile("s_waitcnt vmcnt(3)" ::: "memory");
    else if constexpr (N == 2) asm volatile("s_waitcnt vmcnt(2)" ::: "memory");
    else if constexpr (N == 1) asm volatile("s_waitcnt vmcnt(1)" ::: "memory");
    else                       asm volatile("s_waitcnt vmcnt(0)" ::: "memory");
    __builtin_amdgcn_sched_barrier(0);
}

// issue a weight-fragment load the compiler cannot sink: asm buffer_load_dwordx4.
// Completion is OUR vmcnt bookkeeping (counted waits are FIFO-safe vs compiler loads).
__device__ __forceinline__ void issue_wf(float4& d, unsigned voff, u32x4 rs)
{
    asm volatile("buffer_load_dwordx4 %0, %1, %2, 0 offen"
                 : "=v"(d) : "v"(voff), "s"(rs) : "memory");
}

// ---- d_ws: fp16 weights, fragment-packed ----
// block (ntile*KT + kt) -> 1KB blob; lane l's h8 at byte l*16:
//   W_T[n = ntile*32 + (l&31)][k = kt*16 + (l>>5)*8 + 0..7]
#define OFF_DIN   0          // 8 ntiles, KT=6   (K=96 pad, N=256)
#define OFF_DHID  24576      // 6 x (8 ntiles, KT=16)
#define OFF_FEAT  417792     // 8 ntiles, KT=16  (N=256: Wd_out[k][n+1])
#define OFF_CIN   483328     // 4 ntiles, KT=16  (N=128)
#define OFF_CHID  516096     // 2 x (4 ntiles, KT=8)
#define OFF_COUT  548864     // 1 ntile,  KT=8   (n<3 -> Wc_out[k][n]; else 0)
#define W_TOTAL   552960
// ---- f32 bias fragments after weights: per ntile 32 f32 = [lq][reg j],
//      value = bias[ntile*32 + (j&3) + 8*(j>>2) + 4*lq] ----
#define FB_DIN  0            // 256
#define FB_DHID 256          // 6 x 256
#define FB_FEAT 1792         // 256  (bd_out[n+1])
#define FB_CIN  2048         // 128
#define FB_CHID 2176         // 2 x 128
#define FB_WD0  2432         // 256: Wd_out[k*257]  (density weight column, plain order)
#define FB_BD0  2688         // 1:   bd_out[0]
#define B_TOTAL 2689
#define PREP_TOTAL (W_TOTAL + B_TOTAL)

__global__ void prep_kernel(const float* __restrict__ Wd_in,  const float* __restrict__ Wd_hid,
                            const float* __restrict__ Wd_out, const float* __restrict__ Wc_in,
                            const float* __restrict__ Wc_hid, const float* __restrict__ Wc_out,
                            const float* __restrict__ bd_in,  const float* __restrict__ bd_hid,
                            const float* __restrict__ bd_out, const float* __restrict__ bc_in,
                            const float* __restrict__ bc_hid,
                            _Float16* __restrict__ wdst, float* __restrict__ bdst)
{
    int i = blockIdx.x * 256 + threadIdx.x;
    if (i >= PREP_TOTAL) return;
    if (i < W_TOTAL) {
        float v = 0.f;
        int j, n, k;
        #define DECODE(jj, KTv)  do { int frag = (jj) >> 3; int e = (jj) & 7;          \
                                      int lane = frag & 63; int tk = frag >> 6;         \
                                      int ntl = tk / (KTv); int kt = tk % (KTv);        \
                                      n = ntl * 32 + (lane & 31);                       \
                                      k = kt * 16 + (lane >> 5) * 8 + e; } while (0)
        if (i < OFF_DHID) {
            j = i; DECODE(j, 6);
            if (k < 75) v = Wd_in[k * 256 + n];
        } else if (i < OFF_FEAT) {
            j = i - OFF_DHID; int l = j >> 16; j &= 65535; DECODE(j, 16);
            v = Wd_hid[(l * 256 + k) * 256 + n];
        } else if (i < OFF_CIN) {
            j = i - OFF_FEAT; DECODE(j, 16);
            v = Wd_out[k * 257 + n + 1];
        } else if (i < OFF_CHID) {
            j = i - OFF_CIN; DECODE(j, 16);
            v = Wc_in[k * 128 + n];
        } else if (i < OFF_COUT) {
            j = i - OFF_CHID; int l = j >> 14; j &= 16383; DECODE(j, 8);
            v = Wc_hid[(l * 128 + k) * 128 + n];
        } else {
            j = i - OFF_COUT; DECODE(j, 8);
            if (n < 3) v = Wc_out[k * 3 + n];
        }
        #undef DECODE
        wdst[i] = (_Float16)v;
    } else {
        int b = i - W_TOTAL;
        float v = 0.f;
        #define BDECODE(bb) int ntl = (bb) >> 5; int r5 = (bb) & 31;                   \
                            int lq = r5 >> 4, jj = r5 & 15;                            \
                            int n = ntl * 32 + (jj & 3) + 8 * (jj >> 2) + 4 * lq
        if (b < FB_DHID)      { BDECODE(b); v = bd_in[n]; }
        else if (b < FB_FEAT) { int b2 = b - FB_DHID; int l = b2 >> 8; int bb = b2 & 255;
                                BDECODE(bb); v = bd_hid[l * 256 + n]; }
        else if (b < FB_CIN)  { int bb = b - FB_FEAT; BDECODE(bb); v = bd_out[n + 1]; }
        else if (b < FB_CHID) { int bb = b - FB_CIN; BDECODE(bb); v = bc_in[n]; }
        else if (b < FB_WD0)  { int b2 = b - FB_CHID; int l = b2 >> 7; int bb = b2 & 127;
                                BDECODE(bb); v = bc_hid[l * 128 + n]; }
        else if (b < FB_BD0)  { int k = b - FB_WD0; v = Wd_out[k * 257]; }
        else                  { v = bd_out[0]; }
        #undef BDECODE
        bdst[b] = v;
    }
}

__device__ __forceinline__ h8 lds_read_h8(const _Float16* p)
{
    h4 lo = *(const h4*)(p);
    h4 hi = *(const h4*)(p + 4);
    return __builtin_shufflevector(lo, hi, 0, 1, 2, 3, 4, 5, 6, 7);
}

// Compile-time kt iteration, issue-depth D=3, 4-slot register queue (D+1 slots:
// consume kt&3 while (kt+1..kt+3)&3 are in flight -- all distinct).
// Per iter: issue wf(kt+3) [asm], read af(kt) [LDS], counted vm_wait (never 0
// mid-loop), sched_barrier fence, 2*NT MFMAs.
template<int KT, int NT, int KTI>
__device__ __forceinline__ void kt_iter(_Float16 (*At)[KPAD], u32x4 rs,
                                        unsigned bo, int lrow, int lq,
                                        float4 (*wq)[NT], f32x16 (*acc)[NT])
{
    if constexpr (KTI >= KT) {
        return;
    } else {
        constexpr int D = 3;
        if constexpr (KTI + D < KT) {
#pragma unroll
            for (int nt = 0; nt < NT; ++nt)
                issue_wf(wq[(KTI + D) & 3][nt],
                         bo + (unsigned)((nt * KT + KTI + D) * 1024), rs);
        }
        const int koff = KTI * 16 + lq * 8;
        h8 af0 = lds_read_h8(&At[lrow][koff]);
        h8 af1 = lds_read_h8(&At[32 + lrow][koff]);
        constexpr int AHEAD = ((KT - 1 - KTI) < D) ? (KT - 1 - KTI) : D;
        vm_wait<NT * AHEAD>();
#pragma unroll
        for (int nt = 0; nt < NT; ++nt) {
            h8 w = __builtin_bit_cast(h8, wq[KTI & 3][nt]);
            acc[0][nt] = __builtin_amdgcn_mfma_f32_32x32x16_f16(w, af0, acc[0][nt], 0, 0, 0);
            acc[1][nt] = __builtin_amdgcn_mfma_f32_32x32x16_f16(w, af1, acc[1][nt], 0, 0, 0);
        }
        kt_iter<KT, NT, KTI + 1>(At, rs, bo, lrow, lq, wq, acc);
    }
}

// One dense layer, 4 waves / 64 points. Wave c: ntiles c*NT..c*NT+NT-1, rows 0..63.
// Weight loads asm-issued 3 kt ahead into a 4-slot register queue; counted vmcnt.
// acc initialized with fragment-packed bias. Packed-f16 epilogue.
// DDOT: before the barrier, density partial dot (k-slice [c*64, c*64+64)).
template<int KT, int NT, bool RELU, bool DDOT>
__device__ __forceinline__ void dense(_Float16 (*At)[KPAD], u32x4 rs, unsigned wboff,
                                      const float* __restrict__ bfrag,
                                      const float* __restrict__ wd0,
                                      float (*dpart)[64],
                                      int c, int lrow, int lq, int lane)
{
    const int ntile0 = c * NT;
    f32x16 acc[2][NT];
#pragma unroll
    for (int nt = 0; nt < NT; ++nt) {
        f32x16 b = *(const f32x16*)(bfrag + (ntile0 + nt) * 32 + lq * 16);
        acc[0][nt] = b;
        acc[1][nt] = b;
    }

    const unsigned bo = wboff + (unsigned)(ntile0 * KT) * 1024u + (unsigned)(lane * 16);
    float4 wq[4][NT];

    // prologue: issue kt = 0..2
#pragma unroll
    for (int kt = 0; kt < 3; ++kt)
#pragma unroll
        for (int nt = 0; nt < NT; ++nt)
            issue_wf(wq[kt][nt], bo + (unsigned)((nt * KT + kt) * 1024), rs);

    kt_iter<KT, NT, 0>(At, rs, bo, lrow, lq, wq, acc);

    if (DDOT) {
        // density partial: lane = point m, k-slice [c*64, c*64+64) of current h
        float s = 0.f;
        const float* w0 = wd0 + c * 64;
#pragma unroll
        for (int kk = 0; kk < 64; kk += 8) {
            h8 hv = lds_read_h8(&At[lane][c * 64 + kk]);
#pragma unroll
            for (int e = 0; e < 8; ++e)
                s = fmaf((float)hv[e], w0[kk + e], s);
        }
        dpart[c][lane] = s;
    }

    __syncthreads();   // all reads of At done

#pragma unroll
    for (int mt = 0; mt < 2; ++mt) {
        const int m = mt * 32 + lrow;
#pragma unroll
        for (int nt = 0; nt < NT; ++nt) {
#pragma unroll
            for (int p = 0; p < 4; ++p) {
                const int n0 = (ntile0 + nt) * 32 + p * 8 + lq * 4;
                h2 lo = cvt_pk_h2(acc[mt][nt][4 * p + 0], acc[mt][nt][4 * p + 1]);
                h2 hi = cvt_pk_h2(acc[mt][nt][4 * p + 2], acc[mt][nt][4 * p + 3]);
                h4 hv = __builtin_shufflevector(lo, hi, 0, 1, 2, 3);
                if (RELU) {
                    const h4 zero = {(_Float16)0, (_Float16)0, (_Float16)0, (_Float16)0};
                    hv = __builtin_elementwise_max(hv, zero);
                }
                *(h4*)(&At[m][n0]) = hv;
            }
        }
    }
    __syncthreads();   // At ready for next layer
}

__global__ __launch_bounds__(256, 3)
void ffmlp_kernel(const float* __restrict__ mean, const float* __restrict__ cov,
                  const int* __restrict__ decayscale,
                  const _Float16* __restrict__ wws, const float* __restrict__ bws,
                  const float* __restrict__ bc_out,
                  float* __restrict__ out, int N)
{
    __shared__ __align__(16) _Float16 At[64][KPAD];
    __shared__ float dpart[4][64];

    const int t = threadIdx.x;
    const int c = t >> 6, lane = t & 63;         // 4 waves, wave index = c
    const int lrow = lane & 31, lq = lane >> 5;
    const int p0 = blockIdx.x * 64;
    const u32x4 rs = make_srsrc(wws, (unsigned)W_TOTAL * 2u);

    // ---- Fourier embedding (fp32 math, fp16 store). 4 threads per point. ----
    {
        const int m = t >> 2, q = t & 3;
        const long pt = (long)p0 + m;
        float x0 = 0.f, x1 = 0.f, x2 = 0.f, v0 = 0.f, v1 = 0.f, v2 = 0.f;
        if (pt < N) {
            x0 = mean[pt * 3 + 0]; x1 = mean[pt * 3 + 1]; x2 = mean[pt * 3 + 2];
            v0 = cov[pt * 9 + 0];  v1 = cov[pt * 9 + 4];  v2 = cov[pt * 9 + 8];
        }
        const float dec = (float)(*decayscale);
        if (q == 0) {
            At[m][0] = (_Float16)x0; At[m][1] = (_Float16)x1; At[m][2] = (_Float16)x2;
            for (int k = 75; k < 80; ++k) At[m][k] = (_Float16)0.f;
        } else {
            for (int k = 75 + 5 * q; k < (q == 3 ? 96 : 80 + 5 * q); ++k) At[m][k] = (_Float16)0.f;
        }
        const float xs[3] = {x0, x1, x2}, vs[3] = {v0, v1, v2};
#pragma unroll
        for (int fi = 0; fi < 3; ++fi) {
            const int f = q * 3 + fi;
            const float fs = (float)(1 << f);
            const float wcl = fminf(fmaxf(dec - (float)f, 0.f), 1.f);
            const float win = 0.5f * (1.f - cosf(wcl * PI_F));
#pragma unroll
            for (int d = 0; d < 3; ++d) {
                const float xb = xs[d] * fs;
                const float att = expf(-0.5f * vs[d] * fs * fs) * win;
                float s, co;
                sincosf(xb, &s, &co);
                At[m][3 + 6 * f + d] = (_Float16)(s * att);
                At[m][6 + 6 * f + d] = (_Float16)(co * att);
            }
        }
    }
    __syncthreads();

    // ---- density MLP ----
    dense<6, 2, true, false>(At, rs, OFF_DIN * 2u, bws + FB_DIN, bws, dpart, c, lrow, lq, lane);
#pragma unroll 1
    for (int i = 0; i < 6; ++i)
        dense<16, 2, true, false>(At, rs, (OFF_DHID + i * 65536) * 2u, bws + FB_DHID + i * 256,
                                  bws, dpart, c, lrow, lq, lane);
    // FEAT (no relu) + density partial dot on the pre-overwrite h
    dense<16, 2, false, true>(At, rs, OFF_FEAT * 2u, bws + FB_FEAT, bws + FB_WD0, dpart,
                              c, lrow, lq, lane);

    // ---- color MLP ----
    dense<16, 1, true, false>(At, rs, OFF_CIN * 2u, bws + FB_CIN, bws, dpart, c, lrow, lq, lane);
#pragma unroll 1
    for (int i = 0; i < 2; ++i)
        dense<8, 1, true, false>(At, rs, (OFF_CHID + i * 16384) * 2u, bws + FB_CHID + i * 128,
                                 bws, dpart, c, lrow, lq, lane);

    // ---- output layer: 128 -> 16 (rgb cols 0..2), wave c==0 only ----
    if (c == 0) {
        f32x16 acc[2];
#pragma unroll
        for (int mt = 0; mt < 2; ++mt)
#pragma unroll
            for (int j = 0; j < 16; ++j) acc[mt][j] = 0.f;
        const _Float16* wco = wws + OFF_COUT + (size_t)lane * 8;
#pragma unroll
        for (int kt = 0; kt < 8; ++kt) {
            const int koff = kt * 16 + lq * 8;
            h8 wf = *(const h8*)(wco + (size_t)kt * 512);
#pragma unroll
            for (int mt = 0; mt < 2; ++mt) {
                h8 af = lds_read_h8(&At[mt * 32 + lrow][koff]);
                acc[mt] = __builtin_amdgcn_mfma_f32_32x32x16_f16(wf, af, acc[mt], 0, 0, 0);
            }
        }
        const float bc0 = bc_out[0], bc1 = bc_out[1], bc2 = bc_out[2];
        const float bd0 = bws[FB_BD0];
        if (lq == 0) {
#pragma unroll
            for (int mt = 0; mt < 2; ++mt) {
                const int m = mt * 32 + lrow;
                const long pt = (long)p0 + m;
                if (pt < N) {
                    float4 o;
                    o.x = acc[mt][0] + bc0;
                    o.y = acc[mt][1] + bc1;
                    o.z = acc[mt][2] + bc2;
                    o.w = dpart[0][m] + dpart[1][m] + dpart[2][m] + dpart[3][m] + bd0;
                    *(float4*)(out + pt * 4) = o;
                }
            }
        }
    }
}

extern "C" void kernel_launch(void* const* d_in, const int* in_sizes, int n_in,
                              void* d_out, int out_size, void* d_ws, size_t ws_size,
                              hipStream_t stream)
{
    const float* mean   = (const float*)d_in[0];
    const float* cov    = (const float*)d_in[1];
    const float* Wd_in  = (const float*)d_in[2];
    const float* bd_in  = (const float*)d_in[3];
    const float* Wd_hid = (const float*)d_in[4];
    const float* bd_hid = (const float*)d_in[5];
    const float* Wd_out = (const float*)d_in[6];
    const float* bd_out = (const float*)d_in[7];
    const float* Wc_in  = (const float*)d_in[8];
    const float* bc_in  = (const float*)d_in[9];
    const float* Wc_hid = (const float*)d_in[10];
    const float* bc_hid = (const float*)d_in[11];
    const float* Wc_out = (const float*)d_in[12];
    const float* bc_out = (const float*)d_in[13];
    const int*   decay  = (const int*)d_in[14];

    _Float16* wws = (_Float16*)d_ws;
    float*    bws = (float*)((char*)d_ws + (size_t)W_TOTAL * 2);

    const int N = in_sizes[0] / 3;     // 262144 points

    const int prep_blocks = (PREP_TOTAL + 255) / 256;
    prep_kernel<<<prep_blocks, 256, 0, stream>>>(Wd_in, Wd_hid, Wd_out, Wc_in, Wc_hid, Wc_out,
                                                 bd_in, bd_hid, bd_out, bc_in, bc_hid, wws, bws);

    const int blocks = (N + 63) / 64;
    ffmlp_kernel<<<blocks, 256, 0, stream>>>(mean, cov, decay, wws, bws, bc_out, (float*)d_out, N);
}